// Round 7
// baseline (376.168 us; speedup 1.0000x reference)
//
#include <hip/hip_runtime.h>
#include <math.h>

typedef unsigned short u16;
typedef unsigned int u32;
typedef __attribute__((ext_vector_type(8))) short bf16x8_t;
typedef __attribute__((ext_vector_type(4))) float f32x4_t;

#define S_LEN  2048
#define NH     16
#define DK     64
#define DMODEL 1024
#define MROWS  4096   // B*S

__device__ inline u16 f2b(float f) {
  union { float f; u32 u; } c; c.f = f;
  u32 u = c.u;
  return (u16)((u + 0x7fffu + ((u >> 16) & 1u)) >> 16);  // RNE bf16
}

// ---------------- cast fp32 -> bf16 ----------------
__global__ void cast_bf16_kernel(const float* __restrict__ src, u16* __restrict__ dst, int n) {
  int i = (blockIdx.x * blockDim.x + threadIdx.x) * 4;
  if (i + 3 < n) {
    float4 v = *(const float4*)(src + i);
    ushort4 o;
    o.x = f2b(v.x); o.y = f2b(v.y); o.z = f2b(v.z); o.w = f2b(v.w);
    *(ushort4*)(dst + i) = o;
  }
}

// ---------------- fused transpose+cast of the 4 weights: W [1024][1024] fp32 -> Wt [n][k] bf16 ----------------
__global__ void transpose_cast4_kernel(const float* __restrict__ W0, const float* __restrict__ W1,
                                       const float* __restrict__ W2, const float* __restrict__ W3,
                                       u16* __restrict__ D0, u16* __restrict__ D1,
                                       u16* __restrict__ D2, u16* __restrict__ D3) {
  const float* W; u16* Wt;
  switch (blockIdx.z) {
    case 0: W = W0; Wt = D0; break;
    case 1: W = W1; Wt = D1; break;
    case 2: W = W2; Wt = D2; break;
    default: W = W3; Wt = D3; break;
  }
  __shared__ float tile[32][33];
  int bc = blockIdx.x * 32, br = blockIdx.y * 32;
  int tx = threadIdx.x & 31, ty = threadIdx.x >> 5;  // 256 threads: ty 0..7
  #pragma unroll
  for (int yy = 0; yy < 32; yy += 8)
    tile[ty + yy][tx] = W[(size_t)(br + ty + yy) * DMODEL + bc + tx];
  __syncthreads();
  #pragma unroll
  for (int yy = 0; yy < 32; yy += 8)
    Wt[(size_t)(bc + ty + yy) * DMODEL + br + tx] = f2b(tile[tx][ty + yy]);
}

// ---------------- bias table: btab[h][delta+2047] = bias(h,delta) - 16  (softmax offset folded) ----------------
// (allocated with +256 floats of tail slack: attn stages a fixed 128-wide band and may touch
//  up to index 4143 of the last head's row; staged-but-unused entries are never read in compute)
__global__ void bias_table_kernel(const float* __restrict__ rel_emb, float* __restrict__ btab) {
  int idx = blockIdx.x * 256 + threadIdx.x;
  if (idx >= NH * 4095) return;
  int h = idx / 4095;
  int dpos = idx - h * 4095;
  int delta = dpos - 2047;               // j - i; reference n = i - j
  int ret = (delta > 0) ? 16 : 0;        // (n < 0) * num_buckets(16)
  int n = delta < 0 ? -delta : delta;
  int bucket;
  if (n < 8) {
    bucket = ret + n;
  } else {
    float vf = logf((float)n * 0.125f) / 2.7725887222397811f * 8.0f;
    int vil = 8 + (int)vf;
    bucket = ret + (vil < 15 ? vil : 15);
  }
  btab[idx] = rel_emb[bucket * NH + h] - 16.0f;
}

// ---------------- 128x128 bf16 MFMA GEMM, manual staging + SW pipeline (R5-proven) ----------------
// C[m][n] = sum_k A[m][k] * Bt[n][k].  A [4096][1024] bf16, Bt [N][1024] bf16.
// mode 0: C fp32 [4096][1024] (out projection)
// mode 1: fused QKV: Bt=[3072][1024]; n<1024 -> q16 [bh][s][64]; <2048 -> k16; else vt16 [bh][64][s]
#define GSTR 56   // u16 LDS row stride (112 B): 16B-aligned, 2-way bank aliasing (free per m136)
__global__ __launch_bounds__(256) void gemm128_kernel(const u16* __restrict__ A,
                                                      const u16* __restrict__ Bt,
                                                      float* __restrict__ C,
                                                      u16* __restrict__ q16,
                                                      u16* __restrict__ k16,
                                                      u16* __restrict__ vt16,
                                                      int mode) {
  __shared__ __align__(16) u16 As[128 * GSTR];  // 14 KB
  __shared__ __align__(16) u16 Bs[128 * GSTR];
  const int t = threadIdx.x, w = t >> 6, l = t & 63;
  const int c = l & 15, quad = l >> 4;
  const int m0 = blockIdx.x * 128, n0 = blockIdx.y * 128;
  const int wm = (w & 1) * 64, wn = (w >> 1) * 64;

  // staging: thread t -> rows t>>2 and (t>>2)+64, 16B chunk (t&3)  (full 128x32 coverage)
  const int sr = t >> 2;
  const int k8 = (t & 3) * 8;
  const u16* Ag0 = A  + (size_t)(m0 + sr) * DMODEL + k8;
  const u16* Ag1 = Ag0 + (size_t)64 * DMODEL;
  const u16* Bg0 = Bt + (size_t)(n0 + sr) * DMODEL + k8;
  const u16* Bg1 = Bg0 + (size_t)64 * DMODEL;
  u16* Al0 = As + sr * GSTR + k8;
  u16* Al1 = Al0 + 64 * GSTR;
  u16* Bl0 = Bs + sr * GSTR + k8;
  u16* Bl1 = Bl0 + 64 * GSTR;

  // prefetch k0 = 0
  uint4 a0 = *(const uint4*)Ag0, a1 = *(const uint4*)Ag1;
  uint4 b0 = *(const uint4*)Bg0, b1 = *(const uint4*)Bg1;

  f32x4_t acc[16] = {};
  for (int k0 = 0; k0 < DMODEL; k0 += 32) {
    __syncthreads();   // prior frag reads done
    *(uint4*)Al0 = a0; *(uint4*)Al1 = a1;
    *(uint4*)Bl0 = b0; *(uint4*)Bl1 = b1;
    __syncthreads();
    if (k0 + 32 < DMODEL) {  // prefetch next slab; overlaps MFMAs below
      a0 = *(const uint4*)(Ag0 + k0 + 32);
      a1 = *(const uint4*)(Ag1 + k0 + 32);
      b0 = *(const uint4*)(Bg0 + k0 + 32);
      b1 = *(const uint4*)(Bg1 + k0 + 32);
    }
    bf16x8_t af[4], bfr[4];
    #pragma unroll
    for (int i = 0; i < 4; ++i) {
      af[i]  = *(const bf16x8_t*)(As + (wm + i * 16 + c) * GSTR + quad * 8);
      bfr[i] = *(const bf16x8_t*)(Bs + (wn + i * 16 + c) * GSTR + quad * 8);
    }
    #pragma unroll
    for (int mt = 0; mt < 4; ++mt)
      #pragma unroll
      for (int nt = 0; nt < 4; ++nt)
        acc[mt * 4 + nt] = __builtin_amdgcn_mfma_f32_16x16x32_bf16(af[mt], bfr[nt], acc[mt * 4 + nt], 0, 0, 0);
  }

  // C/D layout: col = lane&15, row = quad*4 + reg
  #pragma unroll
  for (int mt = 0; mt < 4; ++mt) {
    int grow0 = m0 + wm + mt * 16 + quad * 4;
    #pragma unroll
    for (int nt = 0; nt < 4; ++nt) {
      int gcol = n0 + wn + nt * 16 + c;
      f32x4_t v4 = acc[mt * 4 + nt];
      if (mode == 0) {
        #pragma unroll
        for (int r = 0; r < 4; ++r)
          C[(size_t)(grow0 + r) * DMODEL + gcol] = v4[r];
      } else {
        int which = gcol >> 10;
        int cc = gcol & 1023;
        int hh = cc >> 6, dk = cc & 63;
        int b = grow0 >> 11, s0 = grow0 & 2047;
        if (which == 2) {
          ushort4 o;
          o.x = f2b(v4[0]); o.y = f2b(v4[1]); o.z = f2b(v4[2]); o.w = f2b(v4[3]);
          *(ushort4*)(vt16 + (((size_t)(b * NH + hh)) * DK + dk) * S_LEN + s0) = o;
        } else {
          u16* dst = (which == 0 ? q16 : k16) + (((size_t)(b * NH + hh)) * S_LEN + s0) * DK + dk;
          #pragma unroll
          for (int r = 0; r < 4; ++r) dst[(size_t)r * DK] = f2b(v4[r]);
        }
      }
    }
  }
}

// ---------------- MFMA flash attention v4: ZERO barriers, direct-global K/V fragments ----------------
// q,k: bf16 [bh][s][64]; vt: bf16 [bh][64][s]; ctx out: bf16 [b][s][1024]
// B-fragments for QK^T and PV are contiguous-16B-per-lane global loads (2 KB contiguous per
// instruction); 4-wave duplication is served by L1, re-reads across blocks by L2/L3 (proven
// R5: 512 MB issued, 71 MB HBM). P round-trip and bias band live in PER-WAVE LDS regions ->
// wave-synchronous (lgkmcnt only), no __syncthreads in the whole kernel.
#define ASTR 72   // u16 row stride (144 B): 16B-aligned, 2-way-max bank aliasing
__global__ __launch_bounds__(256, 4) void attn_mfma_kernel(const u16* __restrict__ q,
                                                           const u16* __restrict__ k,
                                                           const u16* __restrict__ vt,
                                                           const float* __restrict__ btab,
                                                           u16* __restrict__ ctx) {
  __shared__ __align__(16) u16 Ps[4][16 * ASTR];  // per-wave P tile
  __shared__ float band[4][128];                  // per-wave bias band

  const int t = threadIdx.x;
  const int w = t >> 6, l = t & 63;
  const int c = l & 15, quad = l >> 4;
  const int bh = blockIdx.y;
  const int h = bh & (NH - 1), b = bh >> 4;
  const int q0 = blockIdx.x * 64;

  const u16* qb = q + (size_t)bh * S_LEN * DK;
  const u16* kb = k + (size_t)bh * S_LEN * DK;
  const u16* vb = vt + (size_t)bh * DK * S_LEN;
  // per-wave band: bw[d] = bias(key - qlocal), d = key - (quad*4+r) + 15 in [0,78] used
  // btab idx = (2047 - 15 - q0 - w*16) + kt + d ; staged width 128 (tail slack in btab alloc)
  const float* btp = btab + h * 4095 + (2047 - 15 - q0 - w * 16);

  // Q A-fragments (rows q0 + w*16 + c), registers for whole kernel
  bf16x8_t qfrag[2];
  {
    const u16* qp = qb + (size_t)(q0 + w * 16 + c) * DK + quad * 8;
    qfrag[0] = *(const bf16x8_t*)(qp);
    qfrag[1] = *(const bf16x8_t*)(qp + 32);
  }

  float lp[4] = {0.f, 0.f, 0.f, 0.f};   // per-lane partial row sums (rows quad*4+r)
  f32x4_t O[4] = {};

  u16* Pw = Ps[w];
  float* bw = band[w];
  const int bnd0 = c - quad * 4 + 15;   // + nt*16 - r -> [0,78]

  for (int kt = 0; kt < S_LEN; kt += 64) {
    // ---- wave-local bias band stage (no barrier; lgkmcnt-ordered within wave) ----
    bw[l] = btp[kt + l];
    bw[l + 64] = btp[kt + l + 64];

    // ---- S = Q K^T, K B-frags straight from global ----
    f32x4_t s4[4] = {};
    #pragma unroll
    for (int kc = 0; kc < 2; ++kc) {
      #pragma unroll
      for (int nt = 0; nt < 4; ++nt) {
        bf16x8_t bfr = *(const bf16x8_t*)(kb + (size_t)(kt + nt * 16 + c) * DK + kc * 32 + quad * 8);
        s4[nt] = __builtin_amdgcn_mfma_f32_16x16x32_bf16(qfrag[kc], bfr, s4[nt], 0, 0, 0);
      }
    }

    // ---- p = exp(s + bias - 16); accumulate l; P -> per-wave LDS (half-up bf16) ----
    #pragma unroll
    for (int nt = 0; nt < 4; ++nt) {
      #pragma unroll
      for (int r = 0; r < 4; ++r) {
        float p = __expf(s4[nt][r] + bw[bnd0 + nt * 16 - r]);
        lp[r] += p;
        union { float f; u32 u; } cv; cv.f = p;
        Pw[(quad * 4 + r) * ASTR + nt * 16 + c] = (u16)((cv.u + 0x8000u) >> 16);
      }
    }

    // ---- O += P V: P A-frags from per-wave LDS, V^T B-frags straight from global ----
    #pragma unroll
    for (int kc = 0; kc < 2; ++kc) {
      bf16x8_t afr = *(const bf16x8_t*)(Pw + c * ASTR + kc * 32 + quad * 8);
      #pragma unroll
      for (int nt = 0; nt < 4; ++nt) {
        bf16x8_t bvr = *(const bf16x8_t*)(vb + (size_t)(nt * 16 + c) * S_LEN + kt + kc * 32 + quad * 8);
        O[nt] = __builtin_amdgcn_mfma_f32_16x16x32_bf16(afr, bvr, O[nt], 0, 0, 0);
      }
    }
  }

  // ---- single deferred l reduction + epilogue ----
  #pragma unroll
  for (int off = 1; off < 16; off <<= 1)
    #pragma unroll
    for (int r = 0; r < 4; ++r)
      lp[r] += __shfl_xor(lp[r], off, 64);
  #pragma unroll
  for (int r = 0; r < 4; ++r) {
    float inv = 1.0f / lp[r];
    int s = q0 + w * 16 + quad * 4 + r;
    u16* cp = ctx + ((size_t)(b * S_LEN + s)) * DMODEL + h * DK + c;
    #pragma unroll
    for (int nt = 0; nt < 4; ++nt)
      cp[nt * 16] = f2b(O[nt][r] * inv);
  }
}

extern "C" void kernel_launch(void* const* d_in, const int* in_sizes, int n_in,
                              void* d_out, int out_size, void* d_ws, size_t ws_size,
                              hipStream_t stream) {
  const float* x   = (const float*)d_in[0];
  const float* Wq  = (const float*)d_in[1];
  const float* Wk  = (const float*)d_in[2];
  const float* Wv  = (const float*)d_in[3];
  const float* Wo  = (const float*)d_in[4];
  const float* rel = (const float*)d_in[5];
  float* out = (float*)d_out;

  char* ws = (char*)d_ws;
  size_t off = 0;
  auto carve = [&](size_t bytes) -> char* {
    char* p = ws + off;
    off += (bytes + 255) & ~(size_t)255;
    return p;
  };
  u16*   xb   = (u16*)  carve((size_t)MROWS * DMODEL * 2);       // x bf16
  u16*   Wall = (u16*)  carve((size_t)3 * DMODEL * DMODEL * 2);  // [Wq^T;Wk^T;Wv^T] bf16 [3072][1024]
  u16*   Wto  = (u16*)  carve((size_t)DMODEL * DMODEL * 2);
  u16*   qb16 = (u16*)  carve((size_t)4194304 * 2);              // [bh][s][64] bf16
  u16*   kb16 = (u16*)  carve((size_t)4194304 * 2);
  u16*   vt16 = (u16*)  carve((size_t)4194304 * 2);              // [bh][64][s] bf16
  float* btab = (float*)carve(((size_t)NH * 4095 + 256) * 4);    // +256 tail slack (band stage)
  u16*   ctxb = (u16*)  carve((size_t)4194304 * 2);              // [b][s][1024] bf16

  cast_bf16_kernel<<<4096, 256, 0, stream>>>(x, xb, 4194304);
  dim3 tgrid(32, 32, 4);
  transpose_cast4_kernel<<<tgrid, 256, 0, stream>>>(
      Wq, Wk, Wv, Wo,
      Wall, Wall + (size_t)DMODEL * DMODEL, Wall + (size_t)2 * DMODEL * DMODEL, Wto);
  bias_table_kernel<<<(NH * 4095 + 255) / 256, 256, 0, stream>>>(rel, btab);

  dim3 qkvgrid(32, 24);  // M/128, 3072/128
  gemm128_kernel<<<qkvgrid, 256, 0, stream>>>(xb, Wall, nullptr, qb16, kb16, vt16, 1);

  dim3 agrid(S_LEN / 64, 32);  // q-tiles, B*H
  attn_mfma_kernel<<<agrid, 256, 0, stream>>>(qb16, kb16, vt16, btab, ctxb);

  dim3 ogrid(32, 8);
  gemm128_kernel<<<ogrid, 256, 0, stream>>>(ctxb, Wto, out, nullptr, nullptr, nullptr, 0);
}

// Round 8
// 216.754 us; speedup vs baseline: 1.7355x; 1.7355x over previous
//
#include <hip/hip_runtime.h>
#include <math.h>

typedef unsigned short u16;
typedef unsigned int u32;
typedef __attribute__((ext_vector_type(8))) short bf16x8_t;
typedef __attribute__((ext_vector_type(4))) float f32x4_t;

#define S_LEN  2048
#define NH     16
#define DK     64
#define DMODEL 1024
#define MROWS  4096   // B*S

__device__ inline u16 f2b(float f) {
  union { float f; u32 u; } c; c.f = f;
  u32 u = c.u;
  return (u16)((u + 0x7fffu + ((u >> 16) & 1u)) >> 16);  // RNE bf16
}

// ---------------- fused prep: cast x, transpose+cast 4 weights, bias table ----------------
// grid.x = 4096 (cast) + 4096 (4 transposes) + 256 (bias) = 8448 blocks of 256
__global__ void prep_kernel(const float* __restrict__ x,
                            const float* __restrict__ Wq, const float* __restrict__ Wk,
                            const float* __restrict__ Wv, const float* __restrict__ Wo,
                            const float* __restrict__ rel,
                            u16* __restrict__ xb, u16* __restrict__ Wall,
                            u16* __restrict__ Wto, float* __restrict__ btab) {
  __shared__ float tile[32][33];
  const int bid = blockIdx.x, t = threadIdx.x;
  if (bid < 4096) {
    // cast x fp32 -> bf16
    int i = (bid * 256 + t) * 4;
    float4 v = *(const float4*)(x + i);
    ushort4 o;
    o.x = f2b(v.x); o.y = f2b(v.y); o.z = f2b(v.z); o.w = f2b(v.w);
    *(ushort4*)(xb + i) = o;
  } else if (bid < 8192) {
    int bid2 = bid - 4096;
    int z = bid2 >> 10, rem = bid2 & 1023;
    const float* W; u16* Wt;
    switch (z) {
      case 0: W = Wq; Wt = Wall; break;
      case 1: W = Wk; Wt = Wall + (size_t)DMODEL * DMODEL; break;
      case 2: W = Wv; Wt = Wall + (size_t)2 * DMODEL * DMODEL; break;
      default: W = Wo; Wt = Wto; break;
    }
    int bc = (rem & 31) * 32, br = (rem >> 5) * 32;
    int tx = t & 31, ty = t >> 5;
    #pragma unroll
    for (int yy = 0; yy < 32; yy += 8)
      tile[ty + yy][tx] = W[(size_t)(br + ty + yy) * DMODEL + bc + tx];
    __syncthreads();
    #pragma unroll
    for (int yy = 0; yy < 32; yy += 8)
      Wt[(size_t)(bc + ty + yy) * DMODEL + br + tx] = f2b(tile[tx][ty + yy]);
  } else {
    // bias table: btab[h][delta+2047] = bias(h,delta) - 16 (softmax offset folded)
    int idx = (bid - 8192) * 256 + t;
    if (idx < NH * 4095) {
      int h = idx / 4095;
      int dpos = idx - h * 4095;
      int delta = dpos - 2047;               // j - i; reference n = i - j
      int ret = (delta > 0) ? 16 : 0;
      int n = delta < 0 ? -delta : delta;
      int bucket;
      if (n < 8) {
        bucket = ret + n;
      } else {
        float vf = logf((float)n * 0.125f) / 2.7725887222397811f * 8.0f;
        int vil = 8 + (int)vf;
        bucket = ret + (vil < 15 ? vil : 15);
      }
      btab[idx] = rel[bucket * NH + h] - 16.0f;
    }
  }
}

// ---------------- 128x128 bf16 MFMA GEMM, manual staging + SW pipeline (R5-proven core) ----------------
// C[m][n] = sum_k A[m][k] * Bt[n][k].  A [4096][1024] bf16, Bt [N][1024] bf16.
// mode 0: C fp32 [4096][1024] (out projection)
// mode 1: fused QKV: Bt=[3072][1024]; n<1024 -> q16 [bh][s][64]; <2048 -> k16; else vt16 [bh][64][s]
//         q/k stores go through a per-wave LDS transpose (reusing As/Bs) -> coalesced dwordx4
#define GSTR 56   // u16 LDS row stride (112 B): 16B-aligned, 2-way bank aliasing (free per m136)
__global__ __launch_bounds__(256) void gemm128_kernel(const u16* __restrict__ A,
                                                      const u16* __restrict__ Bt,
                                                      float* __restrict__ C,
                                                      u16* __restrict__ q16,
                                                      u16* __restrict__ k16,
                                                      u16* __restrict__ vt16,
                                                      int mode) {
  __shared__ __align__(16) u16 As[128 * GSTR];  // 14336 B
  __shared__ __align__(16) u16 Bs[128 * GSTR];
  const int t = threadIdx.x, w = t >> 6, l = t & 63;
  const int c = l & 15, quad = l >> 4;
  const int m0 = blockIdx.x * 128, n0 = blockIdx.y * 128;
  const int wm = (w & 1) * 64, wn = (w >> 1) * 64;

  // staging: thread t -> rows t>>2 and (t>>2)+64, 16B chunk (t&3)  (full 128x32 coverage)
  const int sr = t >> 2;
  const int k8 = (t & 3) * 8;
  const u16* Ag0 = A  + (size_t)(m0 + sr) * DMODEL + k8;
  const u16* Ag1 = Ag0 + (size_t)64 * DMODEL;
  const u16* Bg0 = Bt + (size_t)(n0 + sr) * DMODEL + k8;
  const u16* Bg1 = Bg0 + (size_t)64 * DMODEL;
  u16* Al0 = As + sr * GSTR + k8;
  u16* Al1 = Al0 + 64 * GSTR;
  u16* Bl0 = Bs + sr * GSTR + k8;
  u16* Bl1 = Bl0 + 64 * GSTR;

  // prefetch k0 = 0
  uint4 a0 = *(const uint4*)Ag0, a1 = *(const uint4*)Ag1;
  uint4 b0 = *(const uint4*)Bg0, b1 = *(const uint4*)Bg1;

  f32x4_t acc[16] = {};
  for (int k0 = 0; k0 < DMODEL; k0 += 32) {
    __syncthreads();   // prior frag reads done
    *(uint4*)Al0 = a0; *(uint4*)Al1 = a1;
    *(uint4*)Bl0 = b0; *(uint4*)Bl1 = b1;
    __syncthreads();
    if (k0 + 32 < DMODEL) {  // prefetch next slab; overlaps MFMAs below
      a0 = *(const uint4*)(Ag0 + k0 + 32);
      a1 = *(const uint4*)(Ag1 + k0 + 32);
      b0 = *(const uint4*)(Bg0 + k0 + 32);
      b1 = *(const uint4*)(Bg1 + k0 + 32);
    }
    bf16x8_t af[4], bfr[4];
    #pragma unroll
    for (int i = 0; i < 4; ++i) {
      af[i]  = *(const bf16x8_t*)(As + (wm + i * 16 + c) * GSTR + quad * 8);
      bfr[i] = *(const bf16x8_t*)(Bs + (wn + i * 16 + c) * GSTR + quad * 8);
    }
    #pragma unroll
    for (int mt = 0; mt < 4; ++mt)
      #pragma unroll
      for (int nt = 0; nt < 4; ++nt)
        acc[mt * 4 + nt] = __builtin_amdgcn_mfma_f32_16x16x32_bf16(af[mt], bfr[nt], acc[mt * 4 + nt], 0, 0, 0);
  }

  // C/D layout: col = lane&15, row = quad*4 + reg
  const int whichblk = n0 >> 10;   // uniform across block (no 1024-boundary straddle; n0 % 128 == 0)
  if (mode == 0) {
    #pragma unroll
    for (int mt = 0; mt < 4; ++mt) {
      int grow0 = m0 + wm + mt * 16 + quad * 4;
      #pragma unroll
      for (int nt = 0; nt < 4; ++nt) {
        int gcol = n0 + wn + nt * 16 + c;
        #pragma unroll
        for (int r = 0; r < 4; ++r)
          C[(size_t)(grow0 + r) * DMODEL + gcol] = acc[mt * 4 + nt][r];
      }
    }
  } else if (whichblk == 2) {
    // vt [bh][dk][s]: contiguous along s (= acc rows) -> direct ushort4
    #pragma unroll
    for (int mt = 0; mt < 4; ++mt) {
      int grow0 = m0 + wm + mt * 16 + quad * 4;
      int b = grow0 >> 11, s0 = grow0 & 2047;
      #pragma unroll
      for (int nt = 0; nt < 4; ++nt) {
        int cc = (n0 + wn + nt * 16 + c) & 1023;
        int hh = cc >> 6, dk = cc & 63;
        f32x4_t v4 = acc[mt * 4 + nt];
        ushort4 o;
        o.x = f2b(v4[0]); o.y = f2b(v4[1]); o.z = f2b(v4[2]); o.w = f2b(v4[3]);
        *(ushort4*)(vt16 + (((size_t)(b * NH + hh)) * DK + dk) * S_LEN + s0) = o;
      }
    }
  } else {
    // q/k [bh][s][dk]: per-wave LDS transpose (64x64 tile, stride 72), 2 rounds over As/Bs
    u16* tb = (w & 1) ? Bs : As;
    const int base_mw = m0 + wm;
    const int bb = base_mw >> 11, s0g = base_mw & 2047;
    const int cc = (n0 + wn) & 1023;
    const int hh = cc >> 6;
    u16* qk = (whichblk == 0 ? q16 : k16) + (((size_t)(bb * NH + hh)) * S_LEN + s0g) * DK;
    __syncthreads();   // all frag reads of As/Bs complete
    #pragma unroll
    for (int round = 0; round < 2; ++round) {
      if ((w >> 1) == round) {
        #pragma unroll
        for (int mt = 0; mt < 4; ++mt)
          #pragma unroll
          for (int nt = 0; nt < 4; ++nt)
            #pragma unroll
            for (int r = 0; r < 4; ++r)
              tb[(mt * 16 + quad * 4 + r) * 72 + nt * 16 + c] = f2b(acc[mt * 4 + nt][r]);
        // wave-synchronous read-back (own region only), coalesced store
        #pragma unroll
        for (int i = 0; i < 8; ++i) {
          int lrow = i * 8 + (l >> 3);
          int chk = l & 7;
          uint4 vv = *(const uint4*)(tb + lrow * 72 + chk * 8);
          *(uint4*)(qk + (size_t)lrow * DK + chk * 8) = vv;
        }
      }
      __syncthreads();
    }
  }
}

// ---------------- MFMA flash attention (R5 core): single-buffer staging + far-tile const bias ----------------
// q,k: bf16 [bh][s][64]; vt: bf16 [bh][64][s]; ctx out: bf16 [b][s][1024]
#define ASTR 72   // u16 row stride (144 B): 16B-aligned, 2-way-max bank aliasing
__global__ __launch_bounds__(256, 4) void attn_mfma_kernel(const u16* __restrict__ q,
                                                           const u16* __restrict__ k,
                                                           const u16* __restrict__ vt,
                                                           const float* __restrict__ btab,
                                                           u16* __restrict__ ctx) {
  __shared__ __align__(16) u16 Ks[64 * ASTR];
  __shared__ __align__(16) u16 Vts[64 * ASTR];
  __shared__ __align__(16) u16 Ps[4 * 16 * ASTR];
  __shared__ float band[128];

  const int t = threadIdx.x;
  const int w = t >> 6, l = t & 63;
  const int c = l & 15, quad = l >> 4;
  const int bh = blockIdx.y;
  const int h = bh & (NH - 1), b = bh >> 4;
  const int q0 = blockIdx.x * 64;

  const u16* qb = q + (size_t)bh * S_LEN * DK;
  const u16* kb = k + (size_t)bh * S_LEN * DK;
  const u16* vb = vt + (size_t)bh * DK * S_LEN;
  // band[d] = btab[h][2047 + (kt - q0 - 63) + d]
  const float* btp = btab + h * 4095 + (2047 - 63 - q0);

  // Q A-fragments (rows q0 + w*16 + c), registers for whole kernel
  bf16x8_t qfrag[2];
  {
    const u16* qp = qb + (size_t)(q0 + w * 16 + c) * DK + quad * 8;
    qfrag[0] = *(const bf16x8_t*)(qp);
    qfrag[1] = *(const bf16x8_t*)(qp + 32);
  }

  float lp[4] = {0.f, 0.f, 0.f, 0.f};
  f32x4_t O[4] = {};

  // staging (FULL coverage): rows srow, srow+32; 256 thr x 2 x 8 u16 = full 64x64 tile each
  const int srow = t >> 3;
  const int sc8 = (t & 7) * 8;
  const u16* kg0 = kb + (size_t)srow * DK + sc8;
  const u16* kg1 = kg0 + (size_t)32 * DK;
  const u16* vg0 = vb + (size_t)srow * S_LEN + sc8;
  const u16* vg1 = vg0 + (size_t)32 * S_LEN;
  u16* Kl0 = Ks + srow * ASTR + sc8;
  u16* Kl1 = Kl0 + 32 * ASTR;
  u16* Vl0 = Vts + srow * ASTR + sc8;
  u16* Vl1 = Vl0 + 32 * ASTR;
  u16* Pw = Ps + w * 16 * ASTR;
  const int bnd0 = c - (w * 16 + quad * 4) + 63;   // + nt*16 - r -> [0,126]

  // prefetch tile kt=0
  uint4 kr0 = *(const uint4*)kg0, kr1 = *(const uint4*)kg1;
  uint4 vr0 = *(const uint4*)vg0, vr1 = *(const uint4*)vg1;
  float br = (t < 127) ? btp[t] : 0.f;   // tile 0 is near (|0-q0| may be >=192; harmless extra stage)

  for (int kt = 0; kt < S_LEN; kt += 64) {
    const int D = kt - q0;
    const bool far = (D >= 192) || (D <= -192);   // bias constant across tile (bucket saturated)
    *(uint4*)Kl0 = kr0; *(uint4*)Kl1 = kr1;
    *(uint4*)Vl0 = vr0; *(uint4*)Vl1 = vr1;
    if (t < 127) band[t] = br;
    __syncthreads();
    if (kt + 64 < S_LEN) {   // prefetch next tile during compute
      kr0 = *(const uint4*)(kg0 + (size_t)(kt + 64) * DK);
      kr1 = *(const uint4*)(kg1 + (size_t)(kt + 64) * DK);
      vr0 = *(const uint4*)(vg0 + (kt + 64));
      vr1 = *(const uint4*)(vg1 + (kt + 64));
      br = (t < 127) ? btp[kt + 64 + t] : 0.f;
    }

    // ---- S = Q K^T ----
    f32x4_t s4[4] = {};
    #pragma unroll
    for (int kc = 0; kc < 2; ++kc) {
      #pragma unroll
      for (int nt = 0; nt < 4; ++nt) {
        bf16x8_t bfr = *(const bf16x8_t*)(Ks + (nt * 16 + c) * ASTR + kc * 32 + quad * 8);
        s4[nt] = __builtin_amdgcn_mfma_f32_16x16x32_bf16(qfrag[kc], bfr, s4[nt], 0, 0, 0);
      }
    }

    // ---- p = exp(s + bias - 16); accumulate l; P -> per-wave LDS ----
    if (far) {
      const float bf = btp[kt + 63];   // wave-uniform: == bias(D) - 16 for every (q,k) in tile
      #pragma unroll
      for (int nt = 0; nt < 4; ++nt) {
        #pragma unroll
        for (int r = 0; r < 4; ++r) {
          float p = __expf(s4[nt][r] + bf);
          lp[r] += p;
          union { float f; u32 u; } cv; cv.f = p;
          Pw[(quad * 4 + r) * ASTR + nt * 16 + c] = (u16)((cv.u + 0x8000u) >> 16);
        }
      }
    } else {
      #pragma unroll
      for (int nt = 0; nt < 4; ++nt) {
        #pragma unroll
        for (int r = 0; r < 4; ++r) {
          float p = __expf(s4[nt][r] + band[bnd0 + nt * 16 - r]);
          lp[r] += p;
          union { float f; u32 u; } cv; cv.f = p;
          Pw[(quad * 4 + r) * ASTR + nt * 16 + c] = (u16)((cv.u + 0x8000u) >> 16);
        }
      }
    }

    // ---- O += P V (wave-synchronous P round-trip) ----
    #pragma unroll
    for (int kc = 0; kc < 2; ++kc) {
      bf16x8_t afr = *(const bf16x8_t*)(Pw + c * ASTR + kc * 32 + quad * 8);
      #pragma unroll
      for (int nt = 0; nt < 4; ++nt) {
        bf16x8_t bfr = *(const bf16x8_t*)(Vts + (nt * 16 + c) * ASTR + kc * 32 + quad * 8);
        O[nt] = __builtin_amdgcn_mfma_f32_16x16x32_bf16(afr, bfr, O[nt], 0, 0, 0);
      }
    }
    __syncthreads();   // all reads done before next tile's writes
  }

  // ---- single deferred l reduction + epilogue ----
  #pragma unroll
  for (int off = 1; off < 16; off <<= 1)
    #pragma unroll
    for (int r = 0; r < 4; ++r)
      lp[r] += __shfl_xor(lp[r], off, 64);
  #pragma unroll
  for (int r = 0; r < 4; ++r) {
    float inv = 1.0f / lp[r];
    int s = q0 + w * 16 + quad * 4 + r;
    u16* cp = ctx + ((size_t)(b * S_LEN + s)) * DMODEL + h * DK + c;
    #pragma unroll
    for (int nt = 0; nt < 4; ++nt)
      cp[nt * 16] = f2b(O[nt][r] * inv);
  }
}

extern "C" void kernel_launch(void* const* d_in, const int* in_sizes, int n_in,
                              void* d_out, int out_size, void* d_ws, size_t ws_size,
                              hipStream_t stream) {
  const float* x   = (const float*)d_in[0];
  const float* Wq  = (const float*)d_in[1];
  const float* Wk  = (const float*)d_in[2];
  const float* Wv  = (const float*)d_in[3];
  const float* Wo  = (const float*)d_in[4];
  const float* rel = (const float*)d_in[5];
  float* out = (float*)d_out;

  char* ws = (char*)d_ws;
  size_t off = 0;
  auto carve = [&](size_t bytes) -> char* {
    char* p = ws + off;
    off += (bytes + 255) & ~(size_t)255;
    return p;
  };
  u16*   xb   = (u16*)  carve((size_t)MROWS * DMODEL * 2);       // x bf16
  u16*   Wall = (u16*)  carve((size_t)3 * DMODEL * DMODEL * 2);  // [Wq^T;Wk^T;Wv^T] bf16 [3072][1024]
  u16*   Wto  = (u16*)  carve((size_t)DMODEL * DMODEL * 2);
  u16*   qb16 = (u16*)  carve((size_t)4194304 * 2);              // [bh][s][64] bf16
  u16*   kb16 = (u16*)  carve((size_t)4194304 * 2);
  u16*   vt16 = (u16*)  carve((size_t)4194304 * 2);              // [bh][64][s] bf16
  float* btab = (float*)carve(((size_t)NH * 4095 + 256) * 4);    // +tail slack (band stage)
  u16*   ctxb = (u16*)  carve((size_t)4194304 * 2);              // [b][s][1024] bf16

  prep_kernel<<<8448, 256, 0, stream>>>(x, Wq, Wk, Wv, Wo, rel, xb, Wall, Wto, btab);

  dim3 qkvgrid(32, 24);  // M/128, 3072/128
  gemm128_kernel<<<qkvgrid, 256, 0, stream>>>(xb, Wall, nullptr, qb16, kb16, vt16, 1);

  dim3 agrid(S_LEN / 64, 32);  // q-tiles, B*H
  attn_mfma_kernel<<<agrid, 256, 0, stream>>>(qb16, kb16, vt16, btab, ctxb);

  dim3 ogrid(32, 8);
  gemm128_kernel<<<ogrid, 256, 0, stream>>>(ctxb, Wto, out, nullptr, nullptr, nullptr, 0);
}

// Round 9
// 208.606 us; speedup vs baseline: 1.8032x; 1.0391x over previous
//
#include <hip/hip_runtime.h>
#include <math.h>

typedef unsigned short u16;
typedef unsigned int u32;
typedef __attribute__((ext_vector_type(8))) short bf16x8_t;
typedef __attribute__((ext_vector_type(4))) float f32x4_t;

#define S_LEN  2048
#define NH     16
#define DK     64
#define DMODEL 1024
#define MROWS  4096   // B*S
#define LOG2E  1.44269504088896f

__device__ inline u16 f2b(float f) {
  union { float f; u32 u; } c; c.f = f;
  u32 u = c.u;
  return (u16)((u + 0x7fffu + ((u >> 16) & 1u)) >> 16);  // RNE bf16
}

__device__ __forceinline__ float fexp2(float x) {
#if __has_builtin(__builtin_amdgcn_exp2f)
  return __builtin_amdgcn_exp2f(x);
#else
  return exp2f(x);
#endif
}

// ---------------- fused prep: cast x, transpose+cast 4 weights, bias table ----------------
// grid.x = 4096 (cast) + 4096 (4 transposes) + 256 (bias) = 8448 blocks of 256
__global__ void prep_kernel(const float* __restrict__ x,
                            const float* __restrict__ Wq, const float* __restrict__ Wk,
                            const float* __restrict__ Wv, const float* __restrict__ Wo,
                            const float* __restrict__ rel,
                            u16* __restrict__ xb, u16* __restrict__ Wall,
                            u16* __restrict__ Wto, float* __restrict__ btab) {
  __shared__ float tile[32][33];
  const int bid = blockIdx.x, t = threadIdx.x;
  if (bid < 4096) {
    // cast x fp32 -> bf16
    int i = (bid * 256 + t) * 4;
    float4 v = *(const float4*)(x + i);
    ushort4 o;
    o.x = f2b(v.x); o.y = f2b(v.y); o.z = f2b(v.z); o.w = f2b(v.w);
    *(ushort4*)(xb + i) = o;
  } else if (bid < 8192) {
    int bid2 = bid - 4096;
    int z = bid2 >> 10, rem = bid2 & 1023;
    const float* W; u16* Wt;
    switch (z) {
      case 0: W = Wq; Wt = Wall; break;
      case 1: W = Wk; Wt = Wall + (size_t)DMODEL * DMODEL; break;
      case 2: W = Wv; Wt = Wall + (size_t)2 * DMODEL * DMODEL; break;
      default: W = Wo; Wt = Wto; break;
    }
    int bc = (rem & 31) * 32, br = (rem >> 5) * 32;
    int tx = t & 31, ty = t >> 5;
    #pragma unroll
    for (int yy = 0; yy < 32; yy += 8)
      tile[ty + yy][tx] = W[(size_t)(br + ty + yy) * DMODEL + bc + tx];
    __syncthreads();
    #pragma unroll
    for (int yy = 0; yy < 32; yy += 8)
      Wt[(size_t)(bc + ty + yy) * DMODEL + br + tx] = f2b(tile[tx][ty + yy]);
  } else {
    // bias table: btab[h][delta+2047] = (bias(h,delta) - 16) * log2(e)   [exp2-domain]
    int idx = (bid - 8192) * 256 + t;
    if (idx < NH * 4095) {
      int h = idx / 4095;
      int dpos = idx - h * 4095;
      int delta = dpos - 2047;               // j - i; reference n = i - j
      int ret = (delta > 0) ? 16 : 0;
      int n = delta < 0 ? -delta : delta;
      int bucket;
      if (n < 8) {
        bucket = ret + n;
      } else {
        float vf = logf((float)n * 0.125f) / 2.7725887222397811f * 8.0f;
        int vil = 8 + (int)vf;
        bucket = ret + (vil < 15 ? vil : 15);
      }
      btab[idx] = (rel[bucket * NH + h] - 16.0f) * LOG2E;
    }
  }
}

// ---------------- 128x128 bf16 MFMA GEMM, manual staging + SW pipeline (R5-proven core) ----------------
// C[m][n] = sum_k A[m][k] * Bt[n][k].  A [4096][1024] bf16, Bt [N][1024] bf16.
// mode 0: C fp32 [4096][1024] (out projection)
// mode 1: fused QKV: Bt=[3072][1024]; n<1024 -> q16 [bh][s][64]; <2048 -> k16; else vt16 [bh][64][s]
//         q/k stores go through a per-wave LDS transpose (reusing As/Bs) -> coalesced dwordx4
#define GSTR 56   // u16 LDS row stride (112 B): 16B-aligned, 2-way bank aliasing (free per m136)
__global__ __launch_bounds__(256) void gemm128_kernel(const u16* __restrict__ A,
                                                      const u16* __restrict__ Bt,
                                                      float* __restrict__ C,
                                                      u16* __restrict__ q16,
                                                      u16* __restrict__ k16,
                                                      u16* __restrict__ vt16,
                                                      int mode) {
  __shared__ __align__(16) u16 As[128 * GSTR];  // 14336 B
  __shared__ __align__(16) u16 Bs[128 * GSTR];
  const int t = threadIdx.x, w = t >> 6, l = t & 63;
  const int c = l & 15, quad = l >> 4;
  const int m0 = blockIdx.x * 128, n0 = blockIdx.y * 128;
  const int wm = (w & 1) * 64, wn = (w >> 1) * 64;

  // staging: thread t -> rows t>>2 and (t>>2)+64, 16B chunk (t&3)  (full 128x32 coverage)
  const int sr = t >> 2;
  const int k8 = (t & 3) * 8;
  const u16* Ag0 = A  + (size_t)(m0 + sr) * DMODEL + k8;
  const u16* Ag1 = Ag0 + (size_t)64 * DMODEL;
  const u16* Bg0 = Bt + (size_t)(n0 + sr) * DMODEL + k8;
  const u16* Bg1 = Bg0 + (size_t)64 * DMODEL;
  u16* Al0 = As + sr * GSTR + k8;
  u16* Al1 = Al0 + 64 * GSTR;
  u16* Bl0 = Bs + sr * GSTR + k8;
  u16* Bl1 = Bl0 + 64 * GSTR;

  // prefetch k0 = 0
  uint4 a0 = *(const uint4*)Ag0, a1 = *(const uint4*)Ag1;
  uint4 b0 = *(const uint4*)Bg0, b1 = *(const uint4*)Bg1;

  f32x4_t acc[16] = {};
  for (int k0 = 0; k0 < DMODEL; k0 += 32) {
    __syncthreads();   // prior frag reads done
    *(uint4*)Al0 = a0; *(uint4*)Al1 = a1;
    *(uint4*)Bl0 = b0; *(uint4*)Bl1 = b1;
    __syncthreads();
    if (k0 + 32 < DMODEL) {  // prefetch next slab; overlaps MFMAs below
      a0 = *(const uint4*)(Ag0 + k0 + 32);
      a1 = *(const uint4*)(Ag1 + k0 + 32);
      b0 = *(const uint4*)(Bg0 + k0 + 32);
      b1 = *(const uint4*)(Bg1 + k0 + 32);
    }
    bf16x8_t af[4], bfr[4];
    #pragma unroll
    for (int i = 0; i < 4; ++i) {
      af[i]  = *(const bf16x8_t*)(As + (wm + i * 16 + c) * GSTR + quad * 8);
      bfr[i] = *(const bf16x8_t*)(Bs + (wn + i * 16 + c) * GSTR + quad * 8);
    }
    #pragma unroll
    for (int mt = 0; mt < 4; ++mt)
      #pragma unroll
      for (int nt = 0; nt < 4; ++nt)
        acc[mt * 4 + nt] = __builtin_amdgcn_mfma_f32_16x16x32_bf16(af[mt], bfr[nt], acc[mt * 4 + nt], 0, 0, 0);
  }

  // C/D layout: col = lane&15, row = quad*4 + reg
  const int whichblk = n0 >> 10;   // uniform across block
  if (mode == 0) {
    #pragma unroll
    for (int mt = 0; mt < 4; ++mt) {
      int grow0 = m0 + wm + mt * 16 + quad * 4;
      #pragma unroll
      for (int nt = 0; nt < 4; ++nt) {
        int gcol = n0 + wn + nt * 16 + c;
        #pragma unroll
        for (int r = 0; r < 4; ++r)
          C[(size_t)(grow0 + r) * DMODEL + gcol] = acc[mt * 4 + nt][r];
      }
    }
  } else if (whichblk == 2) {
    // vt [bh][dk][s]: contiguous along s (= acc rows) -> direct ushort4
    #pragma unroll
    for (int mt = 0; mt < 4; ++mt) {
      int grow0 = m0 + wm + mt * 16 + quad * 4;
      int b = grow0 >> 11, s0 = grow0 & 2047;
      #pragma unroll
      for (int nt = 0; nt < 4; ++nt) {
        int cc = (n0 + wn + nt * 16 + c) & 1023;
        int hh = cc >> 6, dk = cc & 63;
        f32x4_t v4 = acc[mt * 4 + nt];
        ushort4 o;
        o.x = f2b(v4[0]); o.y = f2b(v4[1]); o.z = f2b(v4[2]); o.w = f2b(v4[3]);
        *(ushort4*)(vt16 + (((size_t)(b * NH + hh)) * DK + dk) * S_LEN + s0) = o;
      }
    }
  } else {
    // q/k [bh][s][dk]: per-wave LDS transpose (64x64 tile, stride 72), 2 rounds over As/Bs
    u16* tb = (w & 1) ? Bs : As;
    const int base_mw = m0 + wm;
    const int bb = base_mw >> 11, s0g = base_mw & 2047;
    const int cc = (n0 + wn) & 1023;
    const int hh = cc >> 6;
    u16* qk = (whichblk == 0 ? q16 : k16) + (((size_t)(bb * NH + hh)) * S_LEN + s0g) * DK;
    __syncthreads();   // all frag reads of As/Bs complete
    #pragma unroll
    for (int round = 0; round < 2; ++round) {
      if ((w >> 1) == round) {
        #pragma unroll
        for (int mt = 0; mt < 4; ++mt)
          #pragma unroll
          for (int nt = 0; nt < 4; ++nt)
            #pragma unroll
            for (int r = 0; r < 4; ++r)
              tb[(mt * 16 + quad * 4 + r) * 72 + nt * 16 + c] = f2b(acc[mt * 4 + nt][r]);
        #pragma unroll
        for (int i = 0; i < 8; ++i) {
          int lrow = i * 8 + (l >> 3);
          int chk = l & 7;
          uint4 vv = *(const uint4*)(tb + lrow * 72 + chk * 8);
          *(uint4*)(qk + (size_t)lrow * DK + chk * 8) = vv;
        }
      }
      __syncthreads();
    }
  }
}

// ---------------- MFMA flash attention v5: 32 queries/wave (128/block), reg-shared K/V frags ----------------
// q,k: bf16 [bh][s][64]; vt: bf16 [bh][64][s]; ctx out: bf16 [b][s][1024]
#define ASTR 72   // u16 row stride (144 B): 16B-aligned, 2-way-max bank aliasing
__global__ __launch_bounds__(256) void attn_mfma_kernel(const u16* __restrict__ q,
                                                        const u16* __restrict__ k,
                                                        const u16* __restrict__ vt,
                                                        const float* __restrict__ btab,
                                                        u16* __restrict__ ctx) {
  __shared__ __align__(16) u16 Ks[64 * ASTR];
  __shared__ __align__(16) u16 Vts[64 * ASTR];
  __shared__ __align__(16) u16 Ps[4][16 * ASTR];  // per-wave 16-row P buffer (reused per q-group)
  __shared__ float band[192];                     // exp2-domain bias for 191 deltas of (128q, 64k) tile

  const int t = threadIdx.x;
  const int w = t >> 6, l = t & 63;
  const int c = l & 15, quad = l >> 4;
  const int bh = blockIdx.y;
  const int h = bh & (NH - 1), b = bh >> 4;
  const int q0 = blockIdx.x * 128;

  const u16* qb = q + (size_t)bh * S_LEN * DK;
  const u16* kb = k + (size_t)bh * S_LEN * DK;
  const u16* vb = vt + (size_t)bh * DK * S_LEN;
  // band[d] = btp[kt + d], delta = d - 127 + (kt - q0); d used in [0,190]
  const float* btp = btab + h * 4095 + (2047 - 127 - q0);

  // Q A-fragments: rows q0 + w*32 + qg*16 + c
  bf16x8_t qfrag[2][2];
  #pragma unroll
  for (int qg = 0; qg < 2; ++qg) {
    const u16* qp = qb + (size_t)(q0 + w * 32 + qg * 16 + c) * DK + quad * 8;
    qfrag[qg][0] = *(const bf16x8_t*)(qp);
    qfrag[qg][1] = *(const bf16x8_t*)(qp + 32);
  }

  float lp[2][4] = {};
  f32x4_t O[2][4] = {};

  // staging (FULL coverage): rows srow, srow+32; 256 thr x 2 x 8 u16 = full 64x64 tile each
  const int srow = t >> 3;
  const int sc8 = (t & 7) * 8;
  const u16* kg0 = kb + (size_t)srow * DK + sc8;
  const u16* kg1 = kg0 + (size_t)32 * DK;
  const u16* vg0 = vb + (size_t)srow * S_LEN + sc8;
  const u16* vg1 = vg0 + (size_t)32 * S_LEN;
  u16* Kl0 = Ks + srow * ASTR + sc8;
  u16* Kl1 = Kl0 + 32 * ASTR;
  u16* Vl0 = Vts + srow * ASTR + sc8;
  u16* Vl1 = Vl0 + 32 * ASTR;
  u16* Pw = Ps[w];

  // prefetch tile kt=0
  uint4 kr0 = *(const uint4*)kg0, kr1 = *(const uint4*)kg1;
  uint4 vr0 = *(const uint4*)vg0, vr1 = *(const uint4*)vg1;
  float br = (t < 192) ? btp[t] : 0.f;

  for (int kt = 0; kt < S_LEN; kt += 64) {
    const int D = kt - q0;
    const bool far = (D >= 256) || (D <= -192);   // all |delta| in tile >= 91 (bucket saturated), same sign
    *(uint4*)Kl0 = kr0; *(uint4*)Kl1 = kr1;
    *(uint4*)Vl0 = vr0; *(uint4*)Vl1 = vr1;
    if (t < 192) band[t] = br;
    __syncthreads();
    if (kt + 64 < S_LEN) {   // prefetch next tile during compute
      kr0 = *(const uint4*)(kg0 + (size_t)(kt + 64) * DK);
      kr1 = *(const uint4*)(kg1 + (size_t)(kt + 64) * DK);
      vr0 = *(const uint4*)(vg0 + (kt + 64));
      vr1 = *(const uint4*)(vg1 + (kt + 64));
      br = (t < 192) ? btp[kt + 64 + t] : 0.f;
    }

    // ---- K B-frags once into regs, shared by both q-groups ----
    bf16x8_t kf[2][4];
    #pragma unroll
    for (int kc = 0; kc < 2; ++kc)
      #pragma unroll
      for (int nt = 0; nt < 4; ++nt)
        kf[kc][nt] = *(const bf16x8_t*)(Ks + (nt * 16 + c) * ASTR + kc * 32 + quad * 8);

    f32x4_t s4[2][4] = {};
    #pragma unroll
    for (int qg = 0; qg < 2; ++qg)
      #pragma unroll
      for (int kc = 0; kc < 2; ++kc)
        #pragma unroll
        for (int nt = 0; nt < 4; ++nt)
          s4[qg][nt] = __builtin_amdgcn_mfma_f32_16x16x32_bf16(qfrag[qg][kc], kf[kc][nt], s4[qg][nt], 0, 0, 0);

    // ---- V B-frags once into regs (kf dead), shared by both q-groups ----
    bf16x8_t vf[2][4];
    #pragma unroll
    for (int kc = 0; kc < 2; ++kc)
      #pragma unroll
      for (int nt = 0; nt < 4; ++nt)
        vf[kc][nt] = *(const bf16x8_t*)(Vts + (nt * 16 + c) * ASTR + kc * 32 + quad * 8);

    const float bfc = band[127];   // far-tile wave-uniform bias (delta = D)
    #pragma unroll
    for (int qg = 0; qg < 2; ++qg) {
      // p = exp2(s*log2e + b'); accumulate l; P -> per-wave 16-row LDS buffer
      const int bnd0 = c - (w * 32 + qg * 16 + quad * 4) + 127;
      if (far) {
        #pragma unroll
        for (int nt = 0; nt < 4; ++nt)
          #pragma unroll
          for (int r = 0; r < 4; ++r) {
            float p = fexp2(fmaf(s4[qg][nt][r], LOG2E, bfc));
            lp[qg][r] += p;
            union { float f; u32 u; } cv; cv.f = p;
            Pw[(quad * 4 + r) * ASTR + nt * 16 + c] = (u16)((cv.u + 0x8000u) >> 16);
          }
      } else {
        #pragma unroll
        for (int nt = 0; nt < 4; ++nt)
          #pragma unroll
          for (int r = 0; r < 4; ++r) {
            float p = fexp2(fmaf(s4[qg][nt][r], LOG2E, band[bnd0 + nt * 16 - r]));
            lp[qg][r] += p;
            union { float f; u32 u; } cv; cv.f = p;
            Pw[(quad * 4 + r) * ASTR + nt * 16 + c] = (u16)((cv.u + 0x8000u) >> 16);
          }
      }
      // O += P V (wave-synchronous P round-trip; WAR on Pw between q-groups is same-wave ordered)
      #pragma unroll
      for (int kc = 0; kc < 2; ++kc) {
        bf16x8_t afr = *(const bf16x8_t*)(Pw + c * ASTR + kc * 32 + quad * 8);
        #pragma unroll
        for (int nt = 0; nt < 4; ++nt)
          O[qg][nt] = __builtin_amdgcn_mfma_f32_16x16x32_bf16(afr, vf[kc][nt], O[qg][nt], 0, 0, 0);
      }
    }
    __syncthreads();   // all reads done before next tile's staging writes
  }

  // ---- single deferred l reduction + epilogue ----
  #pragma unroll
  for (int off = 1; off < 16; off <<= 1)
    #pragma unroll
    for (int qg = 0; qg < 2; ++qg)
      #pragma unroll
      for (int r = 0; r < 4; ++r)
        lp[qg][r] += __shfl_xor(lp[qg][r], off, 64);
  #pragma unroll
  for (int qg = 0; qg < 2; ++qg)
    #pragma unroll
    for (int r = 0; r < 4; ++r) {
      float inv = 1.0f / lp[qg][r];
      int s = q0 + w * 32 + qg * 16 + quad * 4 + r;
      u16* cp = ctx + ((size_t)(b * S_LEN + s)) * DMODEL + h * DK + c;
      #pragma unroll
      for (int nt = 0; nt < 4; ++nt)
        cp[nt * 16] = f2b(O[qg][nt][r] * inv);
    }
}

extern "C" void kernel_launch(void* const* d_in, const int* in_sizes, int n_in,
                              void* d_out, int out_size, void* d_ws, size_t ws_size,
                              hipStream_t stream) {
  const float* x   = (const float*)d_in[0];
  const float* Wq  = (const float*)d_in[1];
  const float* Wk  = (const float*)d_in[2];
  const float* Wv  = (const float*)d_in[3];
  const float* Wo  = (const float*)d_in[4];
  const float* rel = (const float*)d_in[5];
  float* out = (float*)d_out;

  char* ws = (char*)d_ws;
  size_t off = 0;
  auto carve = [&](size_t bytes) -> char* {
    char* p = ws + off;
    off += (bytes + 255) & ~(size_t)255;
    return p;
  };
  u16*   xb   = (u16*)  carve((size_t)MROWS * DMODEL * 2);       // x bf16
  u16*   Wall = (u16*)  carve((size_t)3 * DMODEL * DMODEL * 2);  // [Wq^T;Wk^T;Wv^T] bf16 [3072][1024]
  u16*   Wto  = (u16*)  carve((size_t)DMODEL * DMODEL * 2);
  u16*   qb16 = (u16*)  carve((size_t)4194304 * 2);              // [bh][s][64] bf16
  u16*   kb16 = (u16*)  carve((size_t)4194304 * 2);
  u16*   vt16 = (u16*)  carve((size_t)4194304 * 2);              // [bh][64][s] bf16
  float* btab = (float*)carve(((size_t)NH * 4095 + 256) * 4);    // +tail slack (band stage)
  u16*   ctxb = (u16*)  carve((size_t)4194304 * 2);              // [b][s][1024] bf16

  prep_kernel<<<8448, 256, 0, stream>>>(x, Wq, Wk, Wv, Wo, rel, xb, Wall, Wto, btab);

  dim3 qkvgrid(32, 24);  // M/128, 3072/128
  gemm128_kernel<<<qkvgrid, 256, 0, stream>>>(xb, Wall, nullptr, qb16, kb16, vt16, 1);

  dim3 agrid(S_LEN / 128, 32);  // 128-q tiles, B*H
  attn_mfma_kernel<<<agrid, 256, 0, stream>>>(qb16, kb16, vt16, btab, ctxb);

  dim3 ogrid(32, 8);
  gemm128_kernel<<<ogrid, 256, 0, stream>>>(ctxb, Wto, out, nullptr, nullptr, nullptr, 0);
}